// Round 15
// baseline (110.662 us; speedup 1.0000x reference)
//
#include <hip/hip_runtime.h>

#define BB 4
#define TQ 512
#define TK 512
#define DQ 512
#define UU 256
#define CSC 2.8853900817779268f   // 2*log2(e): Eq=2^(CSC*q), Ek=2^(CSC*k), e^{2y}=Eq*Ek
#define L2E 1.4426950408889634f
#define RQ 4

typedef unsigned short u16;
typedef unsigned int u32;
typedef float f2 __attribute__((ext_vector_type(2)));
typedef short bf16x8 __attribute__((ext_vector_type(8)));
typedef float f32x4 __attribute__((ext_vector_type(4)));

__device__ __forceinline__ float fexp2(float x) { return __builtin_amdgcn_exp2f(x); }
__device__ __forceinline__ float frcp(float x)  { return __builtin_amdgcn_rcpf(x); }
__device__ __forceinline__ u32 pkhi(u32 a, u32 b) { return (b & 0xffff0000u) | (a >> 16); }

// wsplit: transpose+split W1/W2 (fp32 [512k][256n]) -> Wh_t/Wl_t (u16 [256n][512k]).
__global__ __launch_bounds__(256) void wsplit(
    const float* __restrict__ W1, const float* __restrict__ W2,
    u16* __restrict__ W1h, u16* __restrict__ W1l,
    u16* __restrict__ W2h, u16* __restrict__ W2l)
{
    __shared__ float tile[32][33];
    const int blk = blockIdx.x, t = threadIdx.x;
    const float* W = (blk >> 7) ? W2 : W1;
    u16* oh = (blk >> 7) ? W2h : W1h;
    u16* ol = (blk >> 7) ? W2l : W1l;
    const int tl = blk & 127;
    const int k0 = (tl >> 3) * 32, n0 = (tl & 7) * 32;
    const int kl = t >> 5, nl = t & 31;
    #pragma unroll
    for (int r = 0; r < 4; r++)
        tile[kl + 8 * r][nl] = W[(size_t)(k0 + kl + 8 * r) * UU + n0 + nl];
    __syncthreads();
    const int nr = t >> 5, kc = t & 31;
    #pragma unroll
    for (int r = 0; r < 4; r++) {
        const float v = tile[kc][nr + 8 * r];
        const u32 x = __float_as_uint(v);
        const u16 h = (u16)(x >> 16);
        const u16 l = (u16)(__float_as_uint(v - __uint_as_float(x & 0xffff0000u)) >> 16);
        oh[(size_t)(n0 + nr + 8 * r) * DQ + k0 + kc] = h;
        ol[(size_t)(n0 + nr + 8 * r) * DQ + k0 + kc] = l;
    }
}

// proj4: C = A@W, split-bf16 MFMA (truncation split, 3 terms), exp2(CSC*acc) epilogue.
// Tile 32m x 64n, K-chunks of 64 (8 iters, 1 barrier each -- half of R13's 16).
// A: global->split->LDS double-buffered. W: pre-split planes, b128 loads issued AFTER
// the barrier (drain at barrier(i+1)). Grid (64,4,2) = 512 blocks, 4 waves each.
// z=0: Eq[m][u] row-major.  z=1: Ek interleaved [b][u/4][j][4] via LDS bounce.
__global__ __launch_bounds__(256) void proj4(
    const float* __restrict__ Aq, const float* __restrict__ Av,
    const u16* __restrict__ W1h, const u16* __restrict__ W1l,
    const u16* __restrict__ W2h, const u16* __restrict__ W2l,
    float* __restrict__ Eq, float* __restrict__ Ek)
{
    __shared__ __align__(16) char raw[18432];   // 2 x 9216: Ah [32][72] + Al [32][72] u16
    float* fin = (float*)raw;                   // [32][68] f32 (8704B), aliases after barrier

    const int z = blockIdx.z;
    const float* A = z ? Av : Aq;
    const u16* Wh = z ? W2h : W1h;
    const u16* Wl = z ? W2l : W1l;

    const int t = threadIdx.x;
    const int m0 = blockIdx.x * 32, n0 = blockIdx.y * 64;
    const int wave = t >> 6, ln = t & 15, qd = (t & 63) >> 4;
    const int arow = t >> 3, ak8 = (t & 7) * 8;        // A staging: 8 fp32/thread
    const int ncol = n0 + wave * 16 + ln;
    const u16* whp = Wh + (size_t)ncol * DQ + qd * 8;
    const u16* wlp = Wl + (size_t)ncol * DQ + qd * 8;

    f32x4 acc[2] = {};

    float4 a40 = *(const float4*)&A[(size_t)(m0 + arow) * DQ + ak8];
    float4 a41 = *(const float4*)&A[(size_t)(m0 + arow) * DQ + ak8 + 4];
    bf16x8 wh0 = *(const bf16x8*)&whp[0];
    bf16x8 wh1 = *(const bf16x8*)&whp[32];
    bf16x8 wl0 = *(const bf16x8*)&wlp[0];
    bf16x8 wl1 = *(const bf16x8*)&wlp[32];

    for (int i = 0; i < DQ / 64; i++) {
        char* buf = raw + (i & 1) * 9216;
        u16* Ah_s = (u16*)buf;
        u16* Al_s = (u16*)(buf + 4608);
        {   // A split -> bf16 hi/lo planes (8 values/thread)
            const float f[8] = {a40.x, a40.y, a40.z, a40.w, a41.x, a41.y, a41.z, a41.w};
            u32 x[8], lx[8];
            #pragma unroll
            for (int e = 0; e < 8; e++) {
                x[e]  = __float_as_uint(f[e]);
                lx[e] = __float_as_uint(f[e] - __uint_as_float(x[e] & 0xffff0000u));
            }
            uint4 hw, lw;
            hw.x = pkhi(x[0], x[1]);  hw.y = pkhi(x[2], x[3]);
            hw.z = pkhi(x[4], x[5]);  hw.w = pkhi(x[6], x[7]);
            lw.x = pkhi(lx[0], lx[1]); lw.y = pkhi(lx[2], lx[3]);
            lw.z = pkhi(lx[4], lx[5]); lw.w = pkhi(lx[6], lx[7]);
            *(uint4*)&Ah_s[arow * 72 + ak8] = hw;
            *(uint4*)&Al_s[arow * 72 + ak8] = lw;
        }
        if (i + 1 < DQ / 64) {   // A prefetch; consumed at stage(i+1), pre-barrier
            const int k0 = (i + 1) * 64;
            a40 = *(const float4*)&A[(size_t)(m0 + arow) * DQ + k0 + ak8];
            a41 = *(const float4*)&A[(size_t)(m0 + arow) * DQ + k0 + ak8 + 4];
        }
        __syncthreads();

        bf16x8 nh0, nh1, nl0, nl1;
        if (i + 1 < DQ / 64) {   // W prefetch AFTER barrier -> drains at barrier(i+1)
            const int k0 = (i + 1) * 64;
            nh0 = *(const bf16x8*)&whp[k0];
            nh1 = *(const bf16x8*)&whp[k0 + 32];
            nl0 = *(const bf16x8*)&wlp[k0];
            nl1 = *(const bf16x8*)&wlp[k0 + 32];
        }

        #pragma unroll
        for (int s = 0; s < 2; s++) {
            const bf16x8 bh = s ? wh1 : wh0;
            const bf16x8 bl = s ? wl1 : wl0;
            bf16x8 ah[2], al[2];
            #pragma unroll
            for (int ii = 0; ii < 2; ii++) {
                const int ar = (ii * 16 + ln) * 72 + s * 32 + qd * 8;
                ah[ii] = *(const bf16x8*)&Ah_s[ar];
                al[ii] = *(const bf16x8*)&Al_s[ar];
            }
            #pragma unroll
            for (int ii = 0; ii < 2; ii++) {
                acc[ii] = __builtin_amdgcn_mfma_f32_16x16x32_bf16(ah[ii], bh, acc[ii], 0, 0, 0);
                acc[ii] = __builtin_amdgcn_mfma_f32_16x16x32_bf16(ah[ii], bl, acc[ii], 0, 0, 0);
                acc[ii] = __builtin_amdgcn_mfma_f32_16x16x32_bf16(al[ii], bh, acc[ii], 0, 0, 0);
            }
        }
        wh0 = nh0; wh1 = nh1; wl0 = nl0; wl1 = nl1;
    }

    if (z == 0) {
        #pragma unroll
        for (int ii = 0; ii < 2; ii++) {
            #pragma unroll
            for (int r = 0; r < 4; r++) {
                const int m = m0 + ii * 16 + qd * 4 + r;
                Eq[(size_t)m * UU + ncol] = fexp2(CSC * acc[ii][r]);
            }
        }
    } else {
        __syncthreads();   // all frag reads done before aliasing staging with fin
        #pragma unroll
        for (int ii = 0; ii < 2; ii++) {
            #pragma unroll
            for (int r = 0; r < 4; r++) {
                const int ml = ii * 16 + qd * 4 + r;          // j-local 0..31
                const int nl = wave * 16 + ln;                // u-local 0..63
                fin[ml * 68 + nl] = fexp2(CSC * acc[ii][r]);
            }
        }
        __syncthreads();
        const int b = m0 >> 9, j0 = m0 & 511;
        #pragma unroll
        for (int p = 0; p < 2; p++) {
            const int idx = p * 256 + t;
            const int jl = idx & 31, u4 = idx >> 5;           // u4 0..15
            const float4 v = *(const float4*)&fin[jl * 68 + u4 * 4];
            ((float4*)Ek)[(size_t)(b * (UU / 4) + (n0 >> 2) + u4) * TK + j0 + jl] = v;
        }
    }
}

// attn+softmax: e^{2y} = Eq*Ek; rcp paired over adjacent u (exact algebra):
// s0/d0 + s1/d1 = (s0*d1+s1*d0)/(d0*d1). shifted_score = -2*sum (shift-invariant).
// Packed inner: d = pk_fma(q2,k2,1) -> 5 VALU + 1 trans per 2 elements.
// k prefetch: NAMED float4 regs, statically indexed (R10's dynamically-indexed kbuf[4]
// got LDS-promoted: 33KB alloca + 1.9e7 bank conflicts -- never index these).
__global__ __launch_bounds__(512) void attn_softmax(
    const float* __restrict__ Eq,    // [BB, TQ, UU]
    const float* __restrict__ Ek,    // [BB, UU/4, TK] of float4 (interleaved u)
    const float* __restrict__ scale, // [UU]
    float* __restrict__ out)         // [BB, TQ, TK]
{
    __shared__ float redbuf[RQ][8];
    const f2 one2 = {1.0f, 1.0f};
    const int t  = threadIdx.x;
    const int b  = blockIdx.x >> 7;            // 128 blocks per b
    const int q0 = (blockIdx.x & 127) * RQ;
    const float*  qrow = Eq + (size_t)(b * TQ + q0) * UU;   // wave-uniform
    const float4* kb4  = (const float4*)Ek + (size_t)b * (UU / 4) * TK + t;

    float acc[RQ] = {};

    auto body = [&](const float4& kv, int g) {
        const float4 sc4 = *(const float4*)&scale[4 * g];    // wave-uniform
        const f2* k2p = (const f2*)&kv;
        const f2* s2p = (const f2*)&sc4;
        #pragma unroll
        for (int r = 0; r < RQ; r++) {
            const float4 q4 = *(const float4*)&qrow[(size_t)r * UU + 4 * g];
            const f2* q2p = (const f2*)&q4;
            #pragma unroll
            for (int p = 0; p < 2; p++) {
                const f2 d = __builtin_elementwise_fma(q2p[p], k2p[p], one2);  // v_pk_fma
                const float num = fmaf(s2p[p].x, d.y, s2p[p].y * d.x);
                acc[r] = fmaf(num, frcp(d.x * d.y), acc[r]);
            }
        }
    };

    float4 c0 = kb4[0];
    float4 c1 = kb4[(size_t)TK];
    float4 c2 = kb4[(size_t)2 * TK];
    float4 c3 = kb4[(size_t)3 * TK];
    for (int g = 0; g < UU / 4; g += 4) {
        float4 n0v, n1v, n2v, n3v;
        if (g + 4 < UU / 4) {
            n0v = kb4[(size_t)(g + 4) * TK];
            n1v = kb4[(size_t)(g + 5) * TK];
            n2v = kb4[(size_t)(g + 6) * TK];
            n3v = kb4[(size_t)(g + 7) * TK];
        }
        body(c0, g); body(c1, g + 1); body(c2, g + 2); body(c3, g + 3);
        c0 = n0v; c1 = n1v; c2 = n2v; c3 = n3v;
    }
    #pragma unroll
    for (int r = 0; r < RQ; r++) acc[r] *= -2.0f;

    const int wave = t >> 6, lane = t & 63;
    float m[RQ], p[RQ];

    // row max over 512 threads
    #pragma unroll
    for (int r = 0; r < RQ; r++) {
        float v = acc[r];
        #pragma unroll
        for (int o = 32; o > 0; o >>= 1) v = fmaxf(v, __shfl_xor(v, o));
        if (lane == 0) redbuf[r][wave] = v;
    }
    __syncthreads();
    #pragma unroll
    for (int r = 0; r < RQ; r++) {
        float v = redbuf[r][0];
        #pragma unroll
        for (int w = 1; w < 8; w++) v = fmaxf(v, redbuf[r][w]);
        m[r] = v;
    }
    __syncthreads();

    // exp and row sum
    #pragma unroll
    for (int r = 0; r < RQ; r++) {
        p[r] = fexp2(L2E * (acc[r] - m[r]));
        float v = p[r];
        #pragma unroll
        for (int o = 32; o > 0; o >>= 1) v += __shfl_xor(v, o);
        if (lane == 0) redbuf[r][wave] = v;
    }
    __syncthreads();
    #pragma unroll
    for (int r = 0; r < RQ; r++) {
        float v = 0.0f;
        #pragma unroll
        for (int w = 0; w < 8; w++) v += redbuf[r][w];
        const float rinv = frcp(v);
        out[(size_t)(b * TQ + q0 + r) * TK + t] = p[r] * rinv;
    }
}

extern "C" void kernel_launch(void* const* d_in, const int* in_sizes, int n_in,
                              void* d_out, int out_size, void* d_ws, size_t ws_size,
                              hipStream_t stream) {
    const float* query = (const float*)d_in[0];
    const float* value = (const float*)d_in[1];
    const float* W1    = (const float*)d_in[2];
    const float* W2    = (const float*)d_in[3];
    const float* scale = (const float*)d_in[4];
    float* out = (float*)d_out;

    float* Eq = (float*)d_ws;                     // [BB*TQ, UU]      2 MB
    float* Ek = Eq + (size_t)BB * TQ * UU;        // [BB,UU/4,TK] f4  2 MB
    char* wbase = (char*)d_ws + 4 * 1048576;      // W planes: 4 x 256 KB
    u16* W1h = (u16*)(wbase);
    u16* W1l = (u16*)(wbase + 262144);
    u16* W2h = (u16*)(wbase + 524288);
    u16* W2l = (u16*)(wbase + 786432);
    (void)ws_size;  // needs 5 MB; harness provides 256 MB (verified R11-R13)

    wsplit<<<256, 256, 0, stream>>>(W1, W2, W1h, W1l, W2h, W2l);
    proj4<<<dim3(64, 4, 2), 256, 0, stream>>>(query, value, W1h, W1l, W2h, W2l, Eq, Ek);
    attn_softmax<<<dim3(BB * TQ / RQ), 512, 0, stream>>>(Eq, Ek, scale, out);
}

// Round 16
// 108.028 us; speedup vs baseline: 1.0244x; 1.0244x over previous
//
#include <hip/hip_runtime.h>

#define BB 4
#define TQ 512
#define TK 512
#define DQ 512
#define UU 256
#define CSC 2.8853900817779268f   // 2*log2(e): Eq=2^(CSC*q), Ek=2^(CSC*k), e^{2y}=Eq*Ek
#define L2E 1.4426950408889634f
#define RQ 4

typedef unsigned short u16;
typedef unsigned int u32;
typedef short bf16x8 __attribute__((ext_vector_type(8)));
typedef float f32x4 __attribute__((ext_vector_type(4)));

__device__ __forceinline__ float fexp2(float x) { return __builtin_amdgcn_exp2f(x); }
__device__ __forceinline__ float frcp(float x)  { return __builtin_amdgcn_rcpf(x); }
__device__ __forceinline__ u32 pkhi(u32 a, u32 b) { return (b & 0xffff0000u) | (a >> 16); }

// wsplit: transpose+split W1/W2 (fp32 [512k][256n]) -> Wh_t/Wl_t (u16 [256n][512k]).
__global__ __launch_bounds__(256) void wsplit(
    const float* __restrict__ W1, const float* __restrict__ W2,
    u16* __restrict__ W1h, u16* __restrict__ W1l,
    u16* __restrict__ W2h, u16* __restrict__ W2l)
{
    __shared__ float tile[32][33];
    const int blk = blockIdx.x, t = threadIdx.x;
    const float* W = (blk >> 7) ? W2 : W1;
    u16* oh = (blk >> 7) ? W2h : W1h;
    u16* ol = (blk >> 7) ? W2l : W1l;
    const int tl = blk & 127;
    const int k0 = (tl >> 3) * 32, n0 = (tl & 7) * 32;
    const int kl = t >> 5, nl = t & 31;
    #pragma unroll
    for (int r = 0; r < 4; r++)
        tile[kl + 8 * r][nl] = W[(size_t)(k0 + kl + 8 * r) * UU + n0 + nl];
    __syncthreads();
    const int nr = t >> 5, kc = t & 31;
    #pragma unroll
    for (int r = 0; r < 4; r++) {
        const float v = tile[kc][nr + 8 * r];
        const u32 x = __float_as_uint(v);
        const u16 h = (u16)(x >> 16);
        const u16 l = (u16)(__float_as_uint(v - __uint_as_float(x & 0xffff0000u)) >> 16);
        oh[(size_t)(n0 + nr + 8 * r) * DQ + k0 + kc] = h;
        ol[(size_t)(n0 + nr + 8 * r) * DQ + k0 + kc] = l;
    }
}

// proj3 (R13 verbatim -- known-good 106.2us config; R15's K=64 variant regressed):
// C = A@W, split-bf16 MFMA (truncation split, 3 terms), exp2(CSC*acc) epilogue.
// Tile 32m x 64n, K chunks of 32. A: global->split->LDS, double-buffered, 1 barrier/iter.
// W: pre-split planes, per-lane b128 global loads, register double-buffer issued AFTER
// the barrier so they drain at barrier(i+1). Grid (64,4,2) = 512 blocks, 4 waves each.
// z=0: Eq[m][u] row-major.  z=1: Ek interleaved [b][u/4][j][4] via LDS bounce.
__global__ __launch_bounds__(256) void proj3(
    const float* __restrict__ Aq, const float* __restrict__ Av,
    const u16* __restrict__ W1h, const u16* __restrict__ W1l,
    const u16* __restrict__ W2h, const u16* __restrict__ W2l,
    float* __restrict__ Eq, float* __restrict__ Ek)
{
    __shared__ __align__(16) char raw[10240];   // 2 x 5120: Ah [32][40] + Al [32][40] u16
    float* fin = (float*)raw;                   // [32][68] f32, aliases after final barrier

    const int z = blockIdx.z;
    const float* A = z ? Av : Aq;
    const u16* Wh = z ? W2h : W1h;
    const u16* Wl = z ? W2l : W1l;

    const int t = threadIdx.x;
    const int m0 = blockIdx.x * 32, n0 = blockIdx.y * 64;
    const int wave = t >> 6, ln = t & 15, qd = (t & 63) >> 4;
    const int arow = t >> 3, ak4 = (t & 7) * 4;        // A staging: 4 fp32/thread
    const int ncol = n0 + wave * 16 + ln;
    const u16* whp = Wh + (size_t)ncol * DQ + qd * 8;
    const u16* wlp = Wl + (size_t)ncol * DQ + qd * 8;

    f32x4 acc[2] = {};

    float4 a4 = *(const float4*)&A[(size_t)(m0 + arow) * DQ + ak4];
    bf16x8 whc = *(const bf16x8*)&whp[0];
    bf16x8 wlc = *(const bf16x8*)&wlp[0];

    for (int i = 0; i < DQ / 32; i++) {
        char* buf = raw + (i & 1) * 5120;
        u16* Ah_s = (u16*)buf;
        u16* Al_s = (u16*)(buf + 2560);
        {   // A split -> bf16 hi/lo planes
            const float f[4] = {a4.x, a4.y, a4.z, a4.w};
            u32 x[4], lx[4];
            #pragma unroll
            for (int e = 0; e < 4; e++) {
                x[e]  = __float_as_uint(f[e]);
                lx[e] = __float_as_uint(f[e] - __uint_as_float(x[e] & 0xffff0000u));
            }
            uint2 hw, lw;
            hw.x = pkhi(x[0], x[1]);  hw.y = pkhi(x[2], x[3]);
            lw.x = pkhi(lx[0], lx[1]); lw.y = pkhi(lx[2], lx[3]);
            *(uint2*)&Ah_s[arow * 40 + ak4] = hw;
            *(uint2*)&Al_s[arow * 40 + ak4] = lw;
        }
        if (i + 1 < DQ / 32)
            a4 = *(const float4*)&A[(size_t)(m0 + arow) * DQ + (i + 1) * 32 + ak4];
        __syncthreads();

        bf16x8 whn, wln;
        if (i + 1 < DQ / 32) {  // W prefetch AFTER barrier -> drains at barrier(i+1)
            whn = *(const bf16x8*)&whp[(i + 1) * 32];
            wln = *(const bf16x8*)&wlp[(i + 1) * 32];
        }

        bf16x8 ah[2], al[2];
        #pragma unroll
        for (int ii = 0; ii < 2; ii++) {
            const int ar = (ii * 16 + ln) * 40 + qd * 8;
            ah[ii] = *(const bf16x8*)&Ah_s[ar];
            al[ii] = *(const bf16x8*)&Al_s[ar];
        }
        #pragma unroll
        for (int ii = 0; ii < 2; ii++) {
            acc[ii] = __builtin_amdgcn_mfma_f32_16x16x32_bf16(ah[ii], whc, acc[ii], 0, 0, 0);
            acc[ii] = __builtin_amdgcn_mfma_f32_16x16x32_bf16(ah[ii], wlc, acc[ii], 0, 0, 0);
            acc[ii] = __builtin_amdgcn_mfma_f32_16x16x32_bf16(al[ii], whc, acc[ii], 0, 0, 0);
        }
        whc = whn; wlc = wln;
    }

    if (z == 0) {
        #pragma unroll
        for (int ii = 0; ii < 2; ii++) {
            #pragma unroll
            for (int r = 0; r < 4; r++) {
                const int m = m0 + ii * 16 + qd * 4 + r;
                Eq[(size_t)m * UU + ncol] = fexp2(CSC * acc[ii][r]);
            }
        }
    } else {
        __syncthreads();
        #pragma unroll
        for (int ii = 0; ii < 2; ii++) {
            #pragma unroll
            for (int r = 0; r < 4; r++) {
                const int ml = ii * 16 + qd * 4 + r;
                const int nl = wave * 16 + ln;
                fin[ml * 68 + nl] = fexp2(CSC * acc[ii][r]);
            }
        }
        __syncthreads();
        const int b = m0 >> 9, j0 = m0 & 511;
        #pragma unroll
        for (int p = 0; p < 2; p++) {
            const int idx = p * 256 + t;
            const int jl = idx & 31, u4 = idx >> 5;
            const float4 v = *(const float4*)&fin[jl * 68 + u4 * 4];
            ((float4*)Ek)[(size_t)(b * (UU / 4) + (n0 >> 2) + u4) * TK + j0 + jl] = v;
        }
    }
}

// attn+softmax (R13 math -- the packed R15 variant regressed): e^{2y} = Eq*Ek;
// rcp paired over adjacent u (exact): s0/d0+s1/d1 = (s0*d1+s1*d0)/(d0*d1).
// shifted_score = -2*sum (softmax shift-invariant). Prefetch loads INTERLEAVED
// between bodies so each ages ~3 bodies before its waitcnt (more L3 latency cover).
// k prefetch: NAMED float4 regs, statically indexed (R10's dynamically-indexed kbuf[4]
// got LDS-promoted: 33KB alloca + 1.9e7 bank conflicts -- never index these).
__global__ __launch_bounds__(512) void attn_softmax(
    const float* __restrict__ Eq,    // [BB, TQ, UU]
    const float* __restrict__ Ek,    // [BB, UU/4, TK] of float4 (interleaved u)
    const float* __restrict__ scale, // [UU]
    float* __restrict__ out)         // [BB, TQ, TK]
{
    __shared__ float redbuf[RQ][8];
    const int t  = threadIdx.x;
    const int b  = blockIdx.x >> 7;            // 128 blocks per b
    const int q0 = (blockIdx.x & 127) * RQ;
    const float*  qrow = Eq + (size_t)(b * TQ + q0) * UU;   // wave-uniform
    const float4* kb4  = (const float4*)Ek + (size_t)b * (UU / 4) * TK + t;

    float acc[RQ] = {};

    auto body = [&](const float4& kv, int g) {
        const float4 sc4 = *(const float4*)&scale[4 * g];    // wave-uniform
        const float* sf = (const float*)&sc4;
        const float* kf = (const float*)&kv;
        #pragma unroll
        for (int r = 0; r < RQ; r++) {
            const float4 q4 = *(const float4*)&qrow[(size_t)r * UU + 4 * g];
            const float* qf = (const float*)&q4;
            #pragma unroll
            for (int p = 0; p < 4; p += 2) {
                const float d0 = fmaf(qf[p],     kf[p],     1.0f);
                const float d1 = fmaf(qf[p + 1], kf[p + 1], 1.0f);
                const float num = fmaf(sf[p], d1, sf[p + 1] * d0);
                acc[r] = fmaf(num, frcp(d0 * d1), acc[r]);
            }
        }
    };

    float4 c0 = kb4[0];
    float4 c1 = kb4[(size_t)TK];
    float4 c2 = kb4[(size_t)2 * TK];
    float4 c3 = kb4[(size_t)3 * TK];
    for (int g = 0; g < UU / 4; g += 4) {
        float4 n0v, n1v, n2v, n3v;
        const bool pf = (g + 4 < UU / 4);
        if (pf) n0v = kb4[(size_t)(g + 4) * TK];
        body(c0, g);
        if (pf) n1v = kb4[(size_t)(g + 5) * TK];
        body(c1, g + 1);
        if (pf) n2v = kb4[(size_t)(g + 6) * TK];
        body(c2, g + 2);
        if (pf) n3v = kb4[(size_t)(g + 7) * TK];
        body(c3, g + 3);
        c0 = n0v; c1 = n1v; c2 = n2v; c3 = n3v;
    }
    #pragma unroll
    for (int r = 0; r < RQ; r++) acc[r] *= -2.0f;

    const int wave = t >> 6, lane = t & 63;
    float m[RQ], p[RQ];

    // row max over 512 threads
    #pragma unroll
    for (int r = 0; r < RQ; r++) {
        float v = acc[r];
        #pragma unroll
        for (int o = 32; o > 0; o >>= 1) v = fmaxf(v, __shfl_xor(v, o));
        if (lane == 0) redbuf[r][wave] = v;
    }
    __syncthreads();
    #pragma unroll
    for (int r = 0; r < RQ; r++) {
        float v = redbuf[r][0];
        #pragma unroll
        for (int w = 1; w < 8; w++) v = fmaxf(v, redbuf[r][w]);
        m[r] = v;
    }
    __syncthreads();

    // exp and row sum
    #pragma unroll
    for (int r = 0; r < RQ; r++) {
        p[r] = fexp2(L2E * (acc[r] - m[r]));
        float v = p[r];
        #pragma unroll
        for (int o = 32; o > 0; o >>= 1) v += __shfl_xor(v, o);
        if (lane == 0) redbuf[r][wave] = v;
    }
    __syncthreads();
    #pragma unroll
    for (int r = 0; r < RQ; r++) {
        float v = 0.0f;
        #pragma unroll
        for (int w = 0; w < 8; w++) v += redbuf[r][w];
        const float rinv = frcp(v);
        out[(size_t)(b * TQ + q0 + r) * TK + t] = p[r] * rinv;
    }
}

extern "C" void kernel_launch(void* const* d_in, const int* in_sizes, int n_in,
                              void* d_out, int out_size, void* d_ws, size_t ws_size,
                              hipStream_t stream) {
    const float* query = (const float*)d_in[0];
    const float* value = (const float*)d_in[1];
    const float* W1    = (const float*)d_in[2];
    const float* W2    = (const float*)d_in[3];
    const float* scale = (const float*)d_in[4];
    float* out = (float*)d_out;

    float* Eq = (float*)d_ws;                     // [BB*TQ, UU]      2 MB
    float* Ek = Eq + (size_t)BB * TQ * UU;        // [BB,UU/4,TK] f4  2 MB
    char* wbase = (char*)d_ws + 4 * 1048576;      // W planes: 4 x 256 KB
    u16* W1h = (u16*)(wbase);
    u16* W1l = (u16*)(wbase + 262144);
    u16* W2h = (u16*)(wbase + 524288);
    u16* W2l = (u16*)(wbase + 786432);
    (void)ws_size;  // needs 5 MB; harness provides 256 MB (verified R11-R13)

    wsplit<<<256, 256, 0, stream>>>(W1, W2, W1h, W1l, W2h, W2l);
    proj3<<<dim3(64, 4, 2), 256, 0, stream>>>(query, value, W1h, W1l, W2h, W2l, Eq, Ek);
    attn_softmax<<<dim3(BB * TQ / RQ), 512, 0, stream>>>(Eq, Ek, scale, out);
}

// Round 17
// 107.941 us; speedup vs baseline: 1.0252x; 1.0008x over previous
//
#include <hip/hip_runtime.h>

#define BB 4
#define TQ 512
#define TK 512
#define DQ 512
#define UU 256
#define CSC 2.8853900817779268f   // 2*log2(e): Eq=2^(CSC*q), Ek=2^(CSC*k), e^{2y}=Eq*Ek
#define L2E 1.4426950408889634f
#define RQ 4

typedef unsigned short u16;
typedef unsigned int u32;
typedef short bf16x8 __attribute__((ext_vector_type(8)));
typedef float f32x4 __attribute__((ext_vector_type(4)));

__device__ __forceinline__ float fexp2(float x) { return __builtin_amdgcn_exp2f(x); }
__device__ __forceinline__ float frcp(float x)  { return __builtin_amdgcn_rcpf(x); }
__device__ __forceinline__ u32 pkhi(u32 a, u32 b) { return (b & 0xffff0000u) | (a >> 16); }

// wsplit: transpose+split W1/W2 (fp32 [512k][256n]) -> Wh_t/Wl_t (u16 [256n][512k]).
__global__ __launch_bounds__(256) void wsplit(
    const float* __restrict__ W1, const float* __restrict__ W2,
    u16* __restrict__ W1h, u16* __restrict__ W1l,
    u16* __restrict__ W2h, u16* __restrict__ W2l)
{
    __shared__ float tile[32][33];
    const int blk = blockIdx.x, t = threadIdx.x;
    const float* W = (blk >> 7) ? W2 : W1;
    u16* oh = (blk >> 7) ? W2h : W1h;
    u16* ol = (blk >> 7) ? W2l : W1l;
    const int tl = blk & 127;
    const int k0 = (tl >> 3) * 32, n0 = (tl & 7) * 32;
    const int kl = t >> 5, nl = t & 31;
    #pragma unroll
    for (int r = 0; r < 4; r++)
        tile[kl + 8 * r][nl] = W[(size_t)(k0 + kl + 8 * r) * UU + n0 + nl];
    __syncthreads();
    const int nr = t >> 5, kc = t & 31;
    #pragma unroll
    for (int r = 0; r < 4; r++) {
        const float v = tile[kc][nr + 8 * r];
        const u32 x = __float_as_uint(v);
        const u16 h = (u16)(x >> 16);
        const u16 l = (u16)(__float_as_uint(v - __uint_as_float(x & 0xffff0000u)) >> 16);
        oh[(size_t)(n0 + nr + 8 * r) * DQ + k0 + kc] = h;
        ol[(size_t)(n0 + nr + 8 * r) * DQ + k0 + kc] = l;
    }
}

// proj3 (R13 verbatim -- best measured config, 106.2us total):
// C = A@W, split-bf16 MFMA (truncation split, 3 terms), exp2(CSC*acc) epilogue.
// Tile 32m x 64n, K chunks of 32. A: global->split->LDS, double-buffered, 1 barrier/iter.
// W: pre-split planes, per-lane b128 global loads, register double-buffer issued AFTER
// the barrier so they drain at barrier(i+1). Grid (64,4,2) = 512 blocks, 4 waves each.
// z=0: Eq[m][u] row-major.  z=1: Ek interleaved [b][u/4][j][4] via LDS bounce.
// (R15's K=64 variant regressed: 2x LDS/regs broke the balance. Keep K=32.)
__global__ __launch_bounds__(256) void proj3(
    const float* __restrict__ Aq, const float* __restrict__ Av,
    const u16* __restrict__ W1h, const u16* __restrict__ W1l,
    const u16* __restrict__ W2h, const u16* __restrict__ W2l,
    float* __restrict__ Eq, float* __restrict__ Ek)
{
    __shared__ __align__(16) char raw[10240];   // 2 x 5120: Ah [32][40] + Al [32][40] u16
    float* fin = (float*)raw;                   // [32][68] f32, aliases after final barrier

    const int z = blockIdx.z;
    const float* A = z ? Av : Aq;
    const u16* Wh = z ? W2h : W1h;
    const u16* Wl = z ? W2l : W1l;

    const int t = threadIdx.x;
    const int m0 = blockIdx.x * 32, n0 = blockIdx.y * 64;
    const int wave = t >> 6, ln = t & 15, qd = (t & 63) >> 4;
    const int arow = t >> 3, ak4 = (t & 7) * 4;        // A staging: 4 fp32/thread
    const int ncol = n0 + wave * 16 + ln;
    const u16* whp = Wh + (size_t)ncol * DQ + qd * 8;
    const u16* wlp = Wl + (size_t)ncol * DQ + qd * 8;

    f32x4 acc[2] = {};

    float4 a4 = *(const float4*)&A[(size_t)(m0 + arow) * DQ + ak4];
    bf16x8 whc = *(const bf16x8*)&whp[0];
    bf16x8 wlc = *(const bf16x8*)&wlp[0];

    for (int i = 0; i < DQ / 32; i++) {
        char* buf = raw + (i & 1) * 5120;
        u16* Ah_s = (u16*)buf;
        u16* Al_s = (u16*)(buf + 2560);
        {   // A split -> bf16 hi/lo planes
            const float f[4] = {a4.x, a4.y, a4.z, a4.w};
            u32 x[4], lx[4];
            #pragma unroll
            for (int e = 0; e < 4; e++) {
                x[e]  = __float_as_uint(f[e]);
                lx[e] = __float_as_uint(f[e] - __uint_as_float(x[e] & 0xffff0000u));
            }
            uint2 hw, lw;
            hw.x = pkhi(x[0], x[1]);  hw.y = pkhi(x[2], x[3]);
            lw.x = pkhi(lx[0], lx[1]); lw.y = pkhi(lx[2], lx[3]);
            *(uint2*)&Ah_s[arow * 40 + ak4] = hw;
            *(uint2*)&Al_s[arow * 40 + ak4] = lw;
        }
        if (i + 1 < DQ / 32)
            a4 = *(const float4*)&A[(size_t)(m0 + arow) * DQ + (i + 1) * 32 + ak4];
        __syncthreads();

        bf16x8 whn, wln;
        if (i + 1 < DQ / 32) {  // W prefetch AFTER barrier -> drains at barrier(i+1)
            whn = *(const bf16x8*)&whp[(i + 1) * 32];
            wln = *(const bf16x8*)&wlp[(i + 1) * 32];
        }

        bf16x8 ah[2], al[2];
        #pragma unroll
        for (int ii = 0; ii < 2; ii++) {
            const int ar = (ii * 16 + ln) * 40 + qd * 8;
            ah[ii] = *(const bf16x8*)&Ah_s[ar];
            al[ii] = *(const bf16x8*)&Al_s[ar];
        }
        #pragma unroll
        for (int ii = 0; ii < 2; ii++) {
            acc[ii] = __builtin_amdgcn_mfma_f32_16x16x32_bf16(ah[ii], whc, acc[ii], 0, 0, 0);
            acc[ii] = __builtin_amdgcn_mfma_f32_16x16x32_bf16(ah[ii], wlc, acc[ii], 0, 0, 0);
            acc[ii] = __builtin_amdgcn_mfma_f32_16x16x32_bf16(al[ii], whc, acc[ii], 0, 0, 0);
        }
        whc = whn; wlc = wln;
    }

    if (z == 0) {
        #pragma unroll
        for (int ii = 0; ii < 2; ii++) {
            #pragma unroll
            for (int r = 0; r < 4; r++) {
                const int m = m0 + ii * 16 + qd * 4 + r;
                Eq[(size_t)m * UU + ncol] = fexp2(CSC * acc[ii][r]);
            }
        }
    } else {
        __syncthreads();
        #pragma unroll
        for (int ii = 0; ii < 2; ii++) {
            #pragma unroll
            for (int r = 0; r < 4; r++) {
                const int ml = ii * 16 + qd * 4 + r;
                const int nl = wave * 16 + ln;
                fin[ml * 68 + nl] = fexp2(CSC * acc[ii][r]);
            }
        }
        __syncthreads();
        const int b = m0 >> 9, j0 = m0 & 511;
        #pragma unroll
        for (int p = 0; p < 2; p++) {
            const int idx = p * 256 + t;
            const int jl = idx & 31, u4 = idx >> 5;
            const float4 v = *(const float4*)&fin[jl * 68 + u4 * 4];
            ((float4*)Ek)[(size_t)(b * (UU / 4) + (n0 >> 2) + u4) * TK + j0 + jl] = v;
        }
    }
}

// attn+softmax (R13 verbatim -- best measured): e^{2y} = Eq*Ek; rcp paired over
// adjacent u (exact): s0/d0+s1/d1 = (s0*d1+s1*d0)/(d0*d1). shifted_score = -2*sum
// (softmax shift-invariant). Prefetch: front-loaded burst of 4 (R16's interleaved
// variant regressed -- burst loads overlap in the memory pipe; keep the burst).
// k prefetch: NAMED float4 regs, statically indexed (R10's dynamically-indexed kbuf[4]
// got LDS-promoted: 33KB alloca + 1.9e7 bank conflicts -- never index these).
__global__ __launch_bounds__(512) void attn_softmax(
    const float* __restrict__ Eq,    // [BB, TQ, UU]
    const float* __restrict__ Ek,    // [BB, UU/4, TK] of float4 (interleaved u)
    const float* __restrict__ scale, // [UU]
    float* __restrict__ out)         // [BB, TQ, TK]
{
    __shared__ float redbuf[RQ][8];
    const int t  = threadIdx.x;
    const int b  = blockIdx.x >> 7;            // 128 blocks per b
    const int q0 = (blockIdx.x & 127) * RQ;
    const float*  qrow = Eq + (size_t)(b * TQ + q0) * UU;   // wave-uniform
    const float4* kb4  = (const float4*)Ek + (size_t)b * (UU / 4) * TK + t;

    float acc[RQ] = {};

    auto body = [&](const float4& kv, int g) {
        const float4 sc4 = *(const float4*)&scale[4 * g];    // wave-uniform
        const float* sf = (const float*)&sc4;
        const float* kf = (const float*)&kv;
        #pragma unroll
        for (int r = 0; r < RQ; r++) {
            const float4 q4 = *(const float4*)&qrow[(size_t)r * UU + 4 * g];
            const float* qf = (const float*)&q4;
            #pragma unroll
            for (int p = 0; p < 4; p += 2) {
                const float d0 = fmaf(qf[p],     kf[p],     1.0f);
                const float d1 = fmaf(qf[p + 1], kf[p + 1], 1.0f);
                const float num = fmaf(sf[p], d1, sf[p + 1] * d0);
                acc[r] = fmaf(num, frcp(d0 * d1), acc[r]);
            }
        }
    };

    float4 c0 = kb4[0];
    float4 c1 = kb4[(size_t)TK];
    float4 c2 = kb4[(size_t)2 * TK];
    float4 c3 = kb4[(size_t)3 * TK];
    for (int g = 0; g < UU / 4; g += 4) {
        float4 n0v, n1v, n2v, n3v;
        if (g + 4 < UU / 4) {
            n0v = kb4[(size_t)(g + 4) * TK];
            n1v = kb4[(size_t)(g + 5) * TK];
            n2v = kb4[(size_t)(g + 6) * TK];
            n3v = kb4[(size_t)(g + 7) * TK];
        }
        body(c0, g); body(c1, g + 1); body(c2, g + 2); body(c3, g + 3);
        c0 = n0v; c1 = n1v; c2 = n2v; c3 = n3v;
    }
    #pragma unroll
    for (int r = 0; r < RQ; r++) acc[r] *= -2.0f;

    const int wave = t >> 6, lane = t & 63;
    float m[RQ], p[RQ];

    // row max over 512 threads
    #pragma unroll
    for (int r = 0; r < RQ; r++) {
        float v = acc[r];
        #pragma unroll
        for (int o = 32; o > 0; o >>= 1) v = fmaxf(v, __shfl_xor(v, o));
        if (lane == 0) redbuf[r][wave] = v;
    }
    __syncthreads();
    #pragma unroll
    for (int r = 0; r < RQ; r++) {
        float v = redbuf[r][0];
        #pragma unroll
        for (int w = 1; w < 8; w++) v = fmaxf(v, redbuf[r][w]);
        m[r] = v;
    }
    __syncthreads();

    // exp and row sum
    #pragma unroll
    for (int r = 0; r < RQ; r++) {
        p[r] = fexp2(L2E * (acc[r] - m[r]));
        float v = p[r];
        #pragma unroll
        for (int o = 32; o > 0; o >>= 1) v += __shfl_xor(v, o);
        if (lane == 0) redbuf[r][wave] = v;
    }
    __syncthreads();
    #pragma unroll
    for (int r = 0; r < RQ; r++) {
        float v = 0.0f;
        #pragma unroll
        for (int w = 0; w < 8; w++) v += redbuf[r][w];
        const float rinv = frcp(v);
        out[(size_t)(b * TQ + q0 + r) * TK + t] = p[r] * rinv;
    }
}

extern "C" void kernel_launch(void* const* d_in, const int* in_sizes, int n_in,
                              void* d_out, int out_size, void* d_ws, size_t ws_size,
                              hipStream_t stream) {
    const float* query = (const float*)d_in[0];
    const float* value = (const float*)d_in[1];
    const float* W1    = (const float*)d_in[2];
    const float* W2    = (const float*)d_in[3];
    const float* scale = (const float*)d_in[4];
    float* out = (float*)d_out;

    float* Eq = (float*)d_ws;                     // [BB*TQ, UU]      2 MB
    float* Ek = Eq + (size_t)BB * TQ * UU;        // [BB,UU/4,TK] f4  2 MB
    char* wbase = (char*)d_ws + 4 * 1048576;      // W planes: 4 x 256 KB
    u16* W1h = (u16*)(wbase);
    u16* W1l = (u16*)(wbase + 262144);
    u16* W2h = (u16*)(wbase + 524288);
    u16* W2l = (u16*)(wbase + 786432);
    (void)ws_size;  // needs 5 MB; harness provides 256 MB (verified R11-R16)

    wsplit<<<256, 256, 0, stream>>>(W1, W2, W1h, W1l, W2h, W2l);
    proj3<<<dim3(64, 4, 2), 256, 0, stream>>>(query, value, W1h, W1l, W2h, W2l, Eq, Ek);
    attn_softmax<<<dim3(BB * TQ / RQ), 512, 0, stream>>>(Eq, Ek, scale, out);
}